// Round 2
// baseline (80.601 us; speedup 1.0000x reference)
//
#include <hip/hip_runtime.h>
#include <hip/hip_fp16.h>

typedef unsigned short ushort_t;
typedef unsigned int uint_t;
typedef __attribute__((ext_vector_type(4))) float f32x4;
typedef __attribute__((ext_vector_type(4))) unsigned int uint4v;
typedef __attribute__((ext_vector_type(2))) _Float16 half2v;
typedef __attribute__((ext_vector_type(2))) __fp16 fp16x2;
typedef __attribute__((ext_vector_type(8))) _Float16 half8;

#if defined(__has_builtin)
#if __has_builtin(__builtin_amdgcn_fdot2)
#define HAVE_FDOT2 1
#endif
#endif

union H8 {
    uint4v u4;
    half8  h8;
    half2v h2[4];
};

// v_cvt_pkrtz_f16_f32 with a bit-cast to _Float16x2 (builtin returns __fp16x2).
__device__ __forceinline__ half2v cvt_pkrtz(float a, float b) {
    fp16x2 r = __builtin_amdgcn_cvt_pkrtz(a, b);
    half2v o;
    __builtin_memcpy(&o, &r, 4);
    return o;
}

// B-fragment gather for 16x16x32 f16 MFMA: lane needs W[r0+i][c], i=0..7
// (k stride = 128 f32 rows). Across the wave each scalar load coalesces as
// 4 x 64B segments (16 consecutive cols per 16-lane group). f32->f16 via
// v_cvt_pkrtz (RTZ; ulp 2^-10 rel, far better than bf16's 2^-8).
__device__ __forceinline__ half8 wfrag(const float* __restrict__ p) {
    H8 u;
    u.h2[0] = cvt_pkrtz(p[0],   p[128]);
    u.h2[1] = cvt_pkrtz(p[256], p[384]);
    u.h2[2] = cvt_pkrtz(p[512], p[640]);
    u.h2[3] = cvt_pkrtz(p[768], p[896]);
    return u.h8;
}

// One fused kernel, zero workspace. Block = (b, 16-row t-tile), 256 thr / 4 waves.
//   stage:  slots[b] -> LDS f16 (row stride 528 B: +16B pad -> 2-way max on
//           frag reads, free per m136), w_head -> half2 LDS.
//   f_proj: 16t x 128h, f16 MFMA, A = feat (cvt in-flight), B = W_f streamed.
//   s_proj: 64n x 128h, f16 MFMA, A = slots LDS, B = W_s streamed; +b_proj;
//           store f16 to s2_lds in [h2][n] half2 layout.
//   phase C: out[t,n] = b_head + sum_h relu(f+s)*w via pk_add/pk_max/v_dot2,
//           f/w reads 4-wide (b128).
__global__ __launch_bounds__(256) void asd_fused(
        const float* __restrict__ feat,
        const float* __restrict__ slots,
        const float* __restrict__ Wproj,
        const float* __restrict__ bproj,
        const float* __restrict__ whead,
        const float* __restrict__ bhead,
        float* __restrict__ out) {
    __shared__ __attribute__((aligned(16))) ushort_t sl_lds[64 * 264]; // 33 KB
    __shared__ __attribute__((aligned(16))) uint_t   s2_lds[64 * 68];  // 17 KB [h2][n]
    __shared__ __attribute__((aligned(16))) ushort_t f_lds[16 * 136];  // 4.25 KB [t][h]
    __shared__ __attribute__((aligned(16))) uint_t   w2_lds[64];

    int tid = threadIdx.x;
    int bid = blockIdx.x;
    int b   = bid >> 6;
    int t0  = (bid & 63) << 4;

    if (tid < 64) {
        half2v wv = cvt_pkrtz(whead[2 * tid], whead[2 * tid + 1]);
        uint_t u;
        __builtin_memcpy(&u, &wv, 4);
        w2_lds[tid] = u;
    }

    // ---- stage slots[b] (64 x 256 f32 = 64 KB, L2-hot) -> f16 LDS ----
    {
        const float* sb = slots + b * (64 * 256);
        #pragma unroll
        for (int k = 0; k < 8; ++k) {
            int g = k * 256 + tid;              // 2048 chunks of 8 f16
            int r = g >> 5, c = g & 31;
            const f32x4* src = (const f32x4*)(sb + r * 256 + c * 8);
            f32x4 v0 = src[0];
            f32x4 v1 = src[1];
            H8 u;
            u.h2[0] = cvt_pkrtz(v0[0], v0[1]);
            u.h2[1] = cvt_pkrtz(v0[2], v0[3]);
            u.h2[2] = cvt_pkrtz(v1[0], v1[1]);
            u.h2[3] = cvt_pkrtz(v1[2], v1[3]);
            *(uint4v*)((char*)sl_lds + r * 528 + c * 16) = u.u4;
        }
    }

    int l = tid & 63, w = tid >> 6;
    int m = l & 15, q = l >> 4;
    int nt0 = 2 * w;
    int c0 = nt0 * 16 + m;                      // this lane's two h-columns
    int c1 = c0 + 16;

    // ---- f_proj: independent of LDS staging, overlaps its latency ----
    f32x4 acc0 = {0.f, 0.f, 0.f, 0.f};
    f32x4 acc1 = {0.f, 0.f, 0.f, 0.f};
    #pragma unroll 2
    for (int kb = 0; kb < 8; ++kb) {
        const float* arow = feat + (b * 1024 + t0 + m) * 256 + kb * 32 + q * 8;
        f32x4 af0 = *(const f32x4*)arow;
        f32x4 af1 = *(const f32x4*)(arow + 4);
        H8 A;
        A.h2[0] = cvt_pkrtz(af0[0], af0[1]);
        A.h2[1] = cvt_pkrtz(af0[2], af0[3]);
        A.h2[2] = cvt_pkrtz(af1[0], af1[1]);
        A.h2[3] = cvt_pkrtz(af1[2], af1[3]);
        const float* wp = Wproj + (kb * 32 + q * 8) * 128;
        half8 B0 = wfrag(wp + c0);
        half8 B1 = wfrag(wp + c1);
        acc0 = __builtin_amdgcn_mfma_f32_16x16x32_f16(A.h8, B0, acc0, 0, 0, 0);
        acc1 = __builtin_amdgcn_mfma_f32_16x16x32_f16(A.h8, B1, acc1, 0, 0, 0);
    }
    #pragma unroll
    for (int r = 0; r < 4; ++r) {
        int row = q * 4 + r;                    // C/D: col=lane&15 -> h, row -> t
        _Float16 v0 = (_Float16)acc0[r];
        _Float16 v1 = (_Float16)acc1[r];
        ushort_t u0, u1;
        __builtin_memcpy(&u0, &v0, 2);
        __builtin_memcpy(&u1, &v1, 2);
        f_lds[row * 136 + c0] = u0;
        f_lds[row * 136 + c1] = u1;
    }
    __syncthreads();                            // sl_lds + f_lds staged

    // ---- s_proj: A from sl_lds, B = W_s streamed from L2 ----
    f32x4 sa[4][2];
    #pragma unroll
    for (int mt = 0; mt < 4; ++mt) {
        sa[mt][0] = (f32x4){0.f, 0.f, 0.f, 0.f};
        sa[mt][1] = (f32x4){0.f, 0.f, 0.f, 0.f};
    }
    const float* Ws = Wproj + 256 * 128;
    #pragma unroll 2
    for (int kb = 0; kb < 8; ++kb) {
        const float* wp = Ws + (kb * 32 + q * 8) * 128;
        half8 B0 = wfrag(wp + c0);
        half8 B1 = wfrag(wp + c1);
        #pragma unroll
        for (int mt = 0; mt < 4; ++mt) {
            half8 As = *(const half8*)((const char*)sl_lds +
                        (mt * 16 + m) * 528 + kb * 64 + q * 16);
            sa[mt][0] = __builtin_amdgcn_mfma_f32_16x16x32_f16(As, B0, sa[mt][0], 0, 0, 0);
            sa[mt][1] = __builtin_amdgcn_mfma_f32_16x16x32_f16(As, B1, sa[mt][1], 0, 0, 0);
        }
    }
    {
        float bp0 = bproj[c0];
        float bp1 = bproj[c1];
        ushort_t* s2s = (ushort_t*)s2_lds;
        int h2a = c0 >> 1, pa = c0 & 1;
        int h2b = c1 >> 1, pb = c1 & 1;
        #pragma unroll
        for (int mt = 0; mt < 4; ++mt) {
            #pragma unroll
            for (int r = 0; r < 4; ++r) {
                int n = mt * 16 + q * 4 + r;    // C/D: row -> n
                _Float16 v0 = (_Float16)(sa[mt][0][r] + bp0);
                _Float16 v1 = (_Float16)(sa[mt][1][r] + bp1);
                ushort_t u0, u1;
                __builtin_memcpy(&u0, &v0, 2);
                __builtin_memcpy(&u1, &v1, 2);
                s2s[h2a * 136 + n * 2 + pa] = u0;
                s2s[h2b * 136 + n * 2 + pb] = u1;
            }
        }
    }
    __syncthreads();                            // s2_lds ready

    // ---- phase C: relu-reduce over h ----
    int t = tid >> 4, ng = tid & 15;            // thread owns (t, n = 4ng..4ng+3)
    const ushort_t* fR = f_lds + t * 136;
    float bh = bhead[0];
    float a0 = bh, a1 = bh, a2 = bh, a3 = bh;
    const half2v hz = {(_Float16)0.f, (_Float16)0.f};
    #pragma unroll 4
    for (int g = 0; g < 16; ++g) {
        uint4v f4 = *(const uint4v*)(fR + g * 8);       // f[t][8g..8g+7]
        uint4v w4 = *(const uint4v*)(w2_lds + g * 4);   // wave-uniform broadcast
        #pragma unroll
        for (int j = 0; j < 4; ++j) {
            int h2 = g * 4 + j;
            uint_t fu = f4[j], wu = w4[j];
            half2v f2, wv;
            __builtin_memcpy(&f2, &fu, 4);
            __builtin_memcpy(&wv, &wu, 4);
            uint4v s4 = *(const uint4v*)(s2_lds + h2 * 68 + 4 * ng);
            float* accs[4] = {&a0, &a1, &a2, &a3};
            #pragma unroll
            for (int j2 = 0; j2 < 4; ++j2) {
                uint_t su = s4[j2];
                half2v sv;
                __builtin_memcpy(&sv, &su, 4);
                half2v x = f2 + sv;
                x = __builtin_elementwise_max(x, hz);
#ifdef HAVE_FDOT2
                *accs[j2] = __builtin_amdgcn_fdot2(x, wv, *accs[j2], false);
#else
                *accs[j2] += (float)x[0] * (float)wv[0] + (float)x[1] * (float)wv[1];
#endif
            }
        }
    }
    f32x4 o = {a0, a1, a2, a3};
    *(f32x4*)(out + (b * 1024 + t0 + t) * 64 + 4 * ng) = o;
}

extern "C" void kernel_launch(void* const* d_in, const int* in_sizes, int n_in,
                              void* d_out, int out_size, void* d_ws, size_t ws_size,
                              hipStream_t stream) {
    const float* feat  = (const float*)d_in[0];  // (8,1024,256) fp32
    const float* slots = (const float*)d_in[1];  // (8,64,256)   fp32
    const float* Wproj = (const float*)d_in[2];  // (512,128)    fp32
    const float* bproj = (const float*)d_in[3];  // (128,)       fp32
    const float* whead = (const float*)d_in[4];  // (128,)       fp32
    const float* bhead = (const float*)d_in[5];  // (1,)         fp32
    float* out = (float*)d_out;                  // (8,1024,64)  fp32

    // Single launch, no workspace: no ws round-trip, no k1->k2 dispatch bubble,
    // and (hypothesis) no 256 MiB ws re-poison inside the timed window.
    hipLaunchKernelGGL(asd_fused, dim3(512), dim3(256), 0, stream,
                       feat, slots, Wproj, bproj, whead, bhead, out);
}